// Round 7
// baseline (2254.194 us; speedup 1.0000x reference)
//
#include <hip/hip_runtime.h>
#include <math.h>

#define MROWS 32768
#define MH    16384      // process M in two halves to fit ws
#define HID   1024
#define KGRU  512

typedef float          f32x4  __attribute__((ext_vector_type(4)));
typedef short          bf16x8 __attribute__((ext_vector_type(8)));
typedef unsigned short u16x4  __attribute__((ext_vector_type(4)));

__device__ __forceinline__ float sigm(float x) { return 1.0f / (1.0f + expf(-x)); }

__device__ __forceinline__ unsigned short f2bf(float f) {
    union { float f; unsigned u; } v; v.f = f;
    unsigned r = v.u + 0x7FFFu + ((v.u >> 16) & 1u);   // RNE
    return (unsigned short)(r >> 16);
}

__device__ __forceinline__ void gld16(const void* g, void* l) {
    __builtin_amdgcn_global_load_lds((const __attribute__((address_space(1))) void*)g,
                                     (__attribute__((address_space(3))) void*)l, 16, 0, 0);
}

// Fused triple-GEMM, bf16 MFMA, 2-phase double-buffered LDS (T3-minimum).
// C_q[m][n] = sum_k A[m][k] * Wq[n][k], q=0..2. Operands swapped in mfma
// (W as A-operand) so per-lane D covers 4 consecutive n at fixed m.
template <int K, bool IS_GRU>
__global__ __launch_bounds__(256, 2) void gemm3(
    const unsigned short* __restrict__ Abf,   // [MH][K] bf16
    const unsigned short* __restrict__ W0,    // [3][HID][K] bf16
    const float* __restrict__ b0, const float* __restrict__ b1, const float* __restrict__ b2,
    const float* __restrict__ bhh,            // GRU only
    float* __restrict__ outF,                 // [MH][HID] fp32, in-place residual
    unsigned short* __restrict__ outBf)       // [MH][HID] bf16 (next step's A)
{
    // 80 KB: 2 buffers x 40 chunks x 1KB. Chunks 0..15 = A, 16..39 = W (fragment-packed).
    __shared__ short L[2][40 * 512];

    const int tid  = threadIdx.x;
    const int lane = tid & 63;
    const int wid  = tid >> 6;
    const int wm   = wid >> 1;       // wave m half (0,1)
    const int wn   = wid & 1;        // wave n half (0,1)
    const int l15  = lane & 15;
    const int l4   = lane >> 4;

    // XCD-aware bijective swizzle (nwg = 2048, divisible by 8)
    const int nwg = gridDim.x;
    const int cpx = nwg >> 3;
    const int wg  = blockIdx.x;
    const int swz = (wg & 7) * cpx + (wg >> 3);
    const int m0  = (swz >> 4) * 128;   // 16 m-panels per XCD -> A panel fits 4MB L2
    const int n0  = (swz & 15) * 64;

    // staging source offsets (elements), fragment-packed mapping
    long aoff[4];
#pragma unroll
    for (int i = 0; i < 4; i++) {
        const int ca = wid * 4 + i;            // chunk = f*2 + ks
        const int f = ca >> 1, ks = ca & 1;
        aoff[i] = (long)(m0 + f * 16 + l15) * K + ks * 32 + l4 * 8;
    }
    long woff[6];
#pragma unroll
    for (int i = 0; i < 6; i++) {
        const int cw = wid * 6 + i;            // chunk = q*8 + nf*2 + ks
        const int q = cw >> 3, nf = (cw >> 1) & 3, ks = cw & 1;
        woff[i] = (long)q * HID * K + (long)(n0 + nf * 16 + l15) * K + ks * 32 + l4 * 8;
    }

    // epilogue coords + residual prefetch (hides the cold fp32 read under the K-loop)
    const int gn0 = n0 + wn * 32 + l4 * 4;
    f32x4 hold[4][2];
    if constexpr (!IS_GRU) {
#pragma unroll
        for (int f = 0; f < 4; f++) {
            const long gm = m0 + wm * 64 + f * 16 + l15;
#pragma unroll
            for (int c = 0; c < 2; c++)
                hold[f][c] = *(const f32x4*)&outF[gm * HID + gn0 + c * 16];
        }
    }

    f32x4 acc[3][2][4];
#pragma unroll
    for (int q = 0; q < 3; q++)
#pragma unroll
        for (int c = 0; c < 2; c++)
#pragma unroll
            for (int f = 0; f < 4; f++) acc[q][c][f] = (f32x4)0.0f;

    auto stage = [&](short* Lw, int k0) {
#pragma unroll
        for (int i = 0; i < 4; i++) gld16(Abf + aoff[i] + k0, Lw + (wid * 4 + i) * 512);
#pragma unroll
        for (int i = 0; i < 6; i++) gld16(W0 + woff[i] + k0, Lw + (16 + wid * 6 + i) * 512);
    };
    auto compute = [&](const short* Lr) {
#pragma unroll
        for (int ks = 0; ks < 2; ks++) {
            bf16x8 ha[4], wb[3][2];
#pragma unroll
            for (int f = 0; f < 4; f++)
                ha[f] = *(const bf16x8*)&Lr[((wm * 4 + f) * 2 + ks) * 512 + lane * 8];
#pragma unroll
            for (int q = 0; q < 3; q++)
#pragma unroll
                for (int c = 0; c < 2; c++)
                    wb[q][c] = *(const bf16x8*)&Lr[(16 + q * 8 + (wn * 2 + c) * 2 + ks) * 512 + lane * 8];
#pragma unroll
            for (int q = 0; q < 3; q++)
#pragma unroll
                for (int c = 0; c < 2; c++)
#pragma unroll
                    for (int f = 0; f < 4; f++)
                        acc[q][c][f] = __builtin_amdgcn_mfma_f32_16x16x32_bf16(
                            wb[q][c], ha[f], acc[q][c][f], 0, 0, 0);
        }
    };

    constexpr int NT = K / 64;   // 8 or 16 (even)

    stage(L[0], 0);
    __syncthreads();             // drain prologue staging

    for (int t = 0; t < NT; t += 2) {
        // phase A: stage t+1 into L[1] (in flight across compute), compute L[0]
        stage(L[1], (t + 1) * 64);
        compute(L[0]);
        __syncthreads();         // waits vmcnt(0): staging overlapped full MFMA phase
        // phase B: stage t+2 into L[0], compute L[1]
        if (t + 2 < NT) stage(L[0], (t + 2) * 64);
        compute(L[1]);
        __syncthreads();
    }

    // ---- epilogue: lane holds (m = m0+wm*64+f*16+l15, n = gn0 + c*16 + r), r=0..3 ----
    const int gn1 = gn0 + 16;
    f32x4 vb[3][2], vh[3][2];
    vb[0][0] = *(const f32x4*)&b0[gn0]; vb[0][1] = *(const f32x4*)&b0[gn1];
    vb[1][0] = *(const f32x4*)&b1[gn0]; vb[1][1] = *(const f32x4*)&b1[gn1];
    vb[2][0] = *(const f32x4*)&b2[gn0]; vb[2][1] = *(const f32x4*)&b2[gn1];
    if constexpr (IS_GRU) {
        vh[0][0] = *(const f32x4*)&bhh[gn0];           vh[0][1] = *(const f32x4*)&bhh[gn1];
        vh[1][0] = *(const f32x4*)&bhh[HID + gn0];     vh[1][1] = *(const f32x4*)&bhh[HID + gn1];
        vh[2][0] = *(const f32x4*)&bhh[2 * HID + gn0]; vh[2][1] = *(const f32x4*)&bhh[2 * HID + gn1];
    }

#pragma unroll
    for (int f = 0; f < 4; f++) {
        const long gm = m0 + wm * 64 + f * 16 + l15;
#pragma unroll
        for (int c = 0; c < 2; c++) {
            const int gn = c ? gn1 : gn0;
            const f32x4 g0 = acc[0][c][f], g1 = acc[1][c][f], g2 = acc[2][c][f];
            f32x4 res;
            if constexpr (IS_GRU) {
#pragma unroll
                for (int j = 0; j < 4; j++) {
                    float r = sigm(g0[j] + vb[0][c][j] + vh[0][c][j]);
                    float z = sigm(g1[j] + vb[1][c][j] + vh[1][c][j]);
                    float n = tanhf(g2[j] + vb[2][c][j] + r * vh[2][c][j]);
                    res[j] = (1.0f - z) * n;
                }
            } else {
#pragma unroll
                for (int j = 0; j < 4; j++) {
                    float hh = tanhf(g0[j] + vb[0][c][j]);
                    float tt = sigm(g1[j] + vb[1][c][j]);
                    float cc = sigm(g2[j] + vb[2][c][j]);
                    res[j] = hh * tt + hold[f][c][j] * (1.0f - cc);
                }
            }
            *(f32x4*)&outF[gm * HID + gn] = res;
            u16x4 rb;
#pragma unroll
            for (int j = 0; j < 4; j++) rb[j] = f2bf(res[j]);
            *(u16x4*)&outBf[gm * HID + gn] = rb;
        }
    }
}

// fp32 -> bf16, plain
__global__ void convP(const float* __restrict__ s, unsigned short* __restrict__ d, int n) {
    int i = (blockIdx.x * blockDim.x + threadIdx.x) * 4;
    const int stride = gridDim.x * blockDim.x * 4;
    for (; i < n; i += stride) {
        f32x4 v = *(const f32x4*)&s[i];
        u16x4 r;
#pragma unroll
        for (int j = 0; j < 4; j++) r[j] = f2bf(v[j]);
        *(u16x4*)&d[i] = r;
    }
}

// fp32 -> bf16, scatter 5 chunks of HID*HID into stride 3*HID*HID (interleave WH/WT/WC)
__global__ void convS(const float* __restrict__ s, unsigned short* __restrict__ d, int n) {
    int i = (blockIdx.x * blockDim.x + threadIdx.x) * 4;
    const int stride = gridDim.x * blockDim.x * 4;
    for (; i < n; i += stride) {
        f32x4 v = *(const f32x4*)&s[i];
        u16x4 r;
#pragma unroll
        for (int j = 0; j < 4; j++) r[j] = f2bf(v[j]);
        const int di = (i >> 20) * (3 * HID * HID) + (i & (HID * HID - 1));
        *(u16x4*)&d[di] = r;
    }
}

extern "C" void kernel_launch(void* const* d_in, const int* in_sizes, int n_in,
                              void* d_out, int out_size, void* d_ws, size_t ws_size,
                              hipStream_t stream) {
    const float* x    = (const float*)d_in[0];
    const float* w_ih = (const float*)d_in[1];
    const float* b_ih = (const float*)d_in[3];
    const float* b_hh = (const float*)d_in[4];
    const float* WH   = (const float*)d_in[5];
    const float* bH   = (const float*)d_in[6];
    const float* WT   = (const float*)d_in[7];
    const float* bT   = (const float*)d_in[8];
    const float* WC   = (const float*)d_in[9];
    const float* bC   = (const float*)d_in[10];

    float* out = (float*)d_out;               // [32768][1024] fp32, in-place h
    char*  ws  = (char*)d_ws;

    // ws layout (bytes): wih_bf 3.1MB | W_bf 31.5MB | ping 33.6MB | pong 33.6MB
    unsigned short* wih_bf = (unsigned short*)ws;
    unsigned short* W_bf   = (unsigned short*)(ws + (size_t)3 * HID * KGRU * 2);
    const size_t off_ping  = (size_t)3 * HID * KGRU * 2 + (size_t)15 * HID * HID * 2;
    unsigned short* ping   = (unsigned short*)(ws + off_ping);
    unsigned short* pong   = (unsigned short*)(ws + off_ping + (size_t)MH * HID * 2);
    // x_bf aliases pong (dead after GRU reads it; step0 then overwrites)

    dim3 blk(256);

    // weight conversions (every call; ws is re-poisoned)
    convP<<<1024, blk, 0, stream>>>(w_ih, wih_bf, 3 * HID * KGRU);
    convS<<<2048, blk, 0, stream>>>(WH, W_bf + 0 * HID * HID, 5 * HID * HID);
    convS<<<2048, blk, 0, stream>>>(WT, W_bf + 1 * HID * HID, 5 * HID * HID);
    convS<<<2048, blk, 0, stream>>>(WC, W_bf + 2 * HID * HID, 5 * HID * HID);

    for (int h = 0; h < 2; h++) {
        const float* xh   = x + (size_t)h * MH * KGRU;
        float*       outh = out + (size_t)h * MH * HID;

        convP<<<2048, blk, 0, stream>>>(xh, pong, MH * KGRU);

        // GRU: A = x_bf(pong), writes fp32 h -> outh, bf16 h -> ping
        gemm3<KGRU, true><<<2048, blk, 0, stream>>>(
            pong, wih_bf, b_ih, b_ih + HID, b_ih + 2 * HID, b_hh, outh, ping);

        // 5 highway steps: bf16 A ping-pongs; fp32 h in-place in outh
        const unsigned short* src = ping;
        for (int s = 0; s < 5; s++) {
            unsigned short* dst = (s & 1) ? ping : pong;
            gemm3<HID, false><<<2048, blk, 0, stream>>>(
                src, W_bf + (size_t)s * 3 * HID * HID,
                bH + s * HID, bT + s * HID, bC + s * HID, nullptr, outh, dst);
            src = dst;
        }
    }
}

// Round 12
// 1932.559 us; speedup vs baseline: 1.1664x; 1.1664x over previous
//
#include <hip/hip_runtime.h>
#include <math.h>

#define MROWS 32768
#define MH    16384      // process M in two halves to fit ws
#define HID   1024
#define KGRU  512

typedef float          f32x4  __attribute__((ext_vector_type(4)));
typedef short          bf16x8 __attribute__((ext_vector_type(8)));
typedef unsigned short u16x4  __attribute__((ext_vector_type(4)));

__device__ __forceinline__ float sigm(float x) { return 1.0f / (1.0f + expf(-x)); }

__device__ __forceinline__ unsigned short f2bf(float f) {
    union { float f; unsigned u; } v; v.f = f;
    unsigned r = v.u + 0x7FFFu + ((v.u >> 16) & 1u);   // RNE
    return (unsigned short)(r >> 16);
}

__device__ __forceinline__ void gld16(const void* g, void* l) {
    __builtin_amdgcn_global_load_lds((const __attribute__((address_space(1))) void*)g,
                                     (__attribute__((address_space(3))) void*)l, 16, 0, 0);
}

// raw barrier + counted vmcnt (compiler must NOT see __syncthreads, else it drains vmcnt(0))
#define SBAR()   asm volatile("s_barrier" ::: "memory")
#define VMCNT4() asm volatile("s_waitcnt vmcnt(4)" ::: "memory")
#define VMCNT0() asm volatile("s_waitcnt vmcnt(0)" ::: "memory")

// Fused triple-GEMM, bf16 MFMA. 3-phase/K-tile schedule, raw s_barrier,
// counted vmcnt gates (T3+T4), setprio around MFMA clusters (T5).
// A triple-buffered (staged 2 tiles ahead), W double-buffered (1 ahead).
// C_q[m][n] = sum_k A[m][k]*Wq[n][k]; W is MFMA A-operand (swapped) so the
// per-lane D covers 4 consecutive n at fixed m (mapping identical to the
// round-3/7 passing kernel).
template <int K, bool IS_GRU>
__global__ __launch_bounds__(512, 2) void gemm3(
    const unsigned short* __restrict__ Abf,   // [MH][K] bf16
    const unsigned short* __restrict__ W0,    // [3][HID][K] bf16
    const float* __restrict__ b0, const float* __restrict__ b1, const float* __restrict__ b2,
    const float* __restrict__ bhh,            // GRU only
    float* __restrict__ outF,                 // [MH][HID] fp32 residual (in/out)
    unsigned short* __restrict__ outBf)       // [MH][HID] bf16 (next step's A)
{
    constexpr int NT = K / 64;
    static_assert(NT >= 3, "pipeline needs >=3 K-tiles");

    // dynamic LDS, 144KB: A = 3 bufs x 32 chunks x 1KB, W = 2 bufs x 24 chunks x 1KB
    extern __shared__ short Lds[];
    short* const Abase = Lds;                  // 3 * 16384 shorts
    short* const Wbase = Lds + 3 * 16384;      // 2 * 12288 shorts

    const int tid  = threadIdx.x;
    const int lane = tid & 63;
    const int wid  = tid >> 6;       // 8 waves
    const int wm   = wid >> 1;       // 0..3  (m quarter)
    const int wn   = wid & 1;        // 0..1  (n half)
    const int l15  = lane & 15;
    const int l4   = lane >> 4;

    // XCD-aware bijective swizzle (nwg = 1024, divisible by 8)
    const int nwg = gridDim.x;
    const int cpx = nwg >> 3;
    const int wg  = blockIdx.x;
    const int swz = (wg & 7) * cpx + (wg >> 3);
    const int m0  = (swz >> 4) * 256;   // 64 m-tiles, n fastest -> A-panel L2 reuse
    const int n0  = (swz & 15) * 64;

    // staging source offsets (bf16 elements), fragment-packed chunks
    long aoff[4];
#pragma unroll
    for (int i = 0; i < 4; i++) {
        const int ca = wid * 4 + i;            // chunk = f*2 + ks, f in [0,16)
        const int f = ca >> 1, ks = ca & 1;
        aoff[i] = (long)(m0 + f * 16 + l15) * K + ks * 32 + l4 * 8;
    }
    long woff[3];
#pragma unroll
    for (int i = 0; i < 3; i++) {              // chunk = q*8 + nf*2 + ks; wave w: (nf,ks)=(w>>1,w&1)
        woff[i] = (long)i * HID * K + (long)(n0 + ((wid >> 1) & 3) * 16 + l15) * K
                + (wid & 1) * 32 + l4 * 8;
    }

    f32x4 acc[3][2][4];
#pragma unroll
    for (int q = 0; q < 3; q++)
#pragma unroll
        for (int c = 0; c < 2; c++)
#pragma unroll
            for (int f = 0; f < 4; f++) acc[q][c][f] = (f32x4)0.0f;

    // ---- prologue: A(0)->buf0, W(0)->wbuf0, A(1)->buf1; gate allows A(1) in flight ----
#pragma unroll
    for (int i = 0; i < 4; i++) gld16(Abf + aoff[i],      Abase + (wid * 4 + i) * 512);
#pragma unroll
    for (int i = 0; i < 3; i++) gld16(W0 + woff[i],       Wbase + (wid + i * 8) * 512);
#pragma unroll
    for (int i = 0; i < 4; i++) gld16(Abf + aoff[i] + 64, Abase + 16384 + (wid * 4 + i) * 512);
    VMCNT4();

    for (int t = 0; t < NT; ++t) {
        const short* At = Abase + (t % 3) * 16384;
        const short* Wc = Wbase + (t & 1) * 12288;

        // ---------- P0: barrier, read ha + wb(q0), issue next-tile staging, MFMA q0 ----------
        SBAR();
        bf16x8 ha[4][2], wb[2][2];
#pragma unroll
        for (int f = 0; f < 4; f++)
#pragma unroll
            for (int ks = 0; ks < 2; ks++)
                ha[f][ks] = *(const bf16x8*)&At[((wm * 4 + f) * 2 + ks) * 512 + lane * 8];
#pragma unroll
        for (int c = 0; c < 2; c++)
#pragma unroll
            for (int ks = 0; ks < 2; ks++)
                wb[c][ks] = *(const bf16x8*)&Wc[((wn * 2 + c) * 2 + ks) * 512 + lane * 8];
        if (t + 1 < NT) {                      // W(t+1) -> other W buffer
            short* Wn = Wbase + ((t + 1) & 1) * 12288;
#pragma unroll
            for (int i = 0; i < 3; i++)
                gld16(W0 + woff[i] + (long)(t + 1) * 64, Wn + (wid + i * 8) * 512);
        }
        if (t + 2 < NT) {                      // A(t+2) -> third A buffer
            short* An = Abase + ((t + 2) % 3) * 16384;
#pragma unroll
            for (int i = 0; i < 4; i++)
                gld16(Abf + aoff[i] + (long)(t + 2) * 64, An + (wid * 4 + i) * 512);
        }
        __builtin_amdgcn_s_setprio(1);
#pragma unroll
        for (int c = 0; c < 2; c++)
#pragma unroll
            for (int f = 0; f < 4; f++)
#pragma unroll
                for (int ks = 0; ks < 2; ks++)
                    acc[0][c][f] = __builtin_amdgcn_mfma_f32_16x16x32_bf16(
                        wb[c][ks], ha[f][ks], acc[0][c][f], 0, 0, 0);
        __builtin_amdgcn_s_setprio(0);

        // ---------- P1: wb(q1), MFMA q1 ----------
        SBAR();
#pragma unroll
        for (int c = 0; c < 2; c++)
#pragma unroll
            for (int ks = 0; ks < 2; ks++)
                wb[c][ks] = *(const bf16x8*)&Wc[(8 + (wn * 2 + c) * 2 + ks) * 512 + lane * 8];
        __builtin_amdgcn_s_setprio(1);
#pragma unroll
        for (int c = 0; c < 2; c++)
#pragma unroll
            for (int f = 0; f < 4; f++)
#pragma unroll
                for (int ks = 0; ks < 2; ks++)
                    acc[1][c][f] = __builtin_amdgcn_mfma_f32_16x16x32_bf16(
                        wb[c][ks], ha[f][ks], acc[1][c][f], 0, 0, 0);
        __builtin_amdgcn_s_setprio(0);

        // ---------- P2: wb(q2), MFMA q2 ----------
        SBAR();
#pragma unroll
        for (int c = 0; c < 2; c++)
#pragma unroll
            for (int ks = 0; ks < 2; ks++)
                wb[c][ks] = *(const bf16x8*)&Wc[(16 + (wn * 2 + c) * 2 + ks) * 512 + lane * 8];
        __builtin_amdgcn_s_setprio(1);
#pragma unroll
        for (int c = 0; c < 2; c++)
#pragma unroll
            for (int f = 0; f < 4; f++)
#pragma unroll
                for (int ks = 0; ks < 2; ks++)
                    acc[2][c][f] = __builtin_amdgcn_mfma_f32_16x16x32_bf16(
                        wb[c][ks], ha[f][ks], acc[2][c][f], 0, 0, 0);
        __builtin_amdgcn_s_setprio(0);

        // pin this tile's reads/MFMA before the boundary (rule #18 WAR window),
        // then counted gate: retire A(t+1)+W(t+1), keep A(t+2) in flight.
        __builtin_amdgcn_sched_barrier(0);
        if (t < NT - 2)       { VMCNT4(); }
        else if (t == NT - 2) { VMCNT0(); }
    }

    // ---- epilogue: lane holds (m = m0+wm*64+f*16+l15, n = gn0 + c*16 + j) ----
    const int gn0 = n0 + wn * 32 + l4 * 4;
    const int gn1 = gn0 + 16;
    f32x4 vb[3][2], vh[3][2];
    vb[0][0] = *(const f32x4*)&b0[gn0]; vb[0][1] = *(const f32x4*)&b0[gn1];
    vb[1][0] = *(const f32x4*)&b1[gn0]; vb[1][1] = *(const f32x4*)&b1[gn1];
    vb[2][0] = *(const f32x4*)&b2[gn0]; vb[2][1] = *(const f32x4*)&b2[gn1];
    if constexpr (IS_GRU) {
        vh[0][0] = *(const f32x4*)&bhh[gn0];           vh[0][1] = *(const f32x4*)&bhh[gn1];
        vh[1][0] = *(const f32x4*)&bhh[HID + gn0];     vh[1][1] = *(const f32x4*)&bhh[HID + gn1];
        vh[2][0] = *(const f32x4*)&bhh[2 * HID + gn0]; vh[2][1] = *(const f32x4*)&bhh[2 * HID + gn1];
    }
    f32x4 hold[4][2];
    if constexpr (!IS_GRU) {
#pragma unroll
        for (int f = 0; f < 4; f++) {
            const long gm = m0 + wm * 64 + f * 16 + l15;
#pragma unroll
            for (int c = 0; c < 2; c++)
                hold[f][c] = *(const f32x4*)&outF[gm * HID + gn0 + c * 16];
        }
    }

#pragma unroll
    for (int f = 0; f < 4; f++) {
        const long gm = m0 + wm * 64 + f * 16 + l15;
#pragma unroll
        for (int c = 0; c < 2; c++) {
            const int gn = c ? gn1 : gn0;
            const f32x4 g0 = acc[0][c][f], g1 = acc[1][c][f], g2 = acc[2][c][f];
            f32x4 res;
            if constexpr (IS_GRU) {
#pragma unroll
                for (int j = 0; j < 4; j++) {
                    float r = sigm(g0[j] + vb[0][c][j] + vh[0][c][j]);
                    float z = sigm(g1[j] + vb[1][c][j] + vh[1][c][j]);
                    float n = tanhf(g2[j] + vb[2][c][j] + r * vh[2][c][j]);
                    res[j] = (1.0f - z) * n;
                }
            } else {
#pragma unroll
                for (int j = 0; j < 4; j++) {
                    float hh = tanhf(g0[j] + vb[0][c][j]);
                    float tt = sigm(g1[j] + vb[1][c][j]);
                    float cc = sigm(g2[j] + vb[2][c][j]);
                    res[j] = hh * tt + hold[f][c][j] * (1.0f - cc);
                }
            }
            *(f32x4*)&outF[gm * HID + gn] = res;
            u16x4 rb;
#pragma unroll
            for (int j = 0; j < 4; j++) rb[j] = f2bf(res[j]);
            *(u16x4*)&outBf[gm * HID + gn] = rb;
        }
    }
}

// fp32 -> bf16, plain
__global__ void convP(const float* __restrict__ s, unsigned short* __restrict__ d, int n) {
    int i = (blockIdx.x * blockDim.x + threadIdx.x) * 4;
    const int stride = gridDim.x * blockDim.x * 4;
    for (; i < n; i += stride) {
        f32x4 v = *(const f32x4*)&s[i];
        u16x4 r;
#pragma unroll
        for (int j = 0; j < 4; j++) r[j] = f2bf(v[j]);
        *(u16x4*)&d[i] = r;
    }
}

// fp32 -> bf16, scatter 5 chunks of HID*HID into stride 3*HID*HID (interleave WH/WT/WC)
__global__ void convS(const float* __restrict__ s, unsigned short* __restrict__ d, int n) {
    int i = (blockIdx.x * blockDim.x + threadIdx.x) * 4;
    const int stride = gridDim.x * blockDim.x * 4;
    for (; i < n; i += stride) {
        f32x4 v = *(const f32x4*)&s[i];
        u16x4 r;
#pragma unroll
        for (int j = 0; j < 4; j++) r[j] = f2bf(v[j]);
        const int di = (i >> 20) * (3 * HID * HID) + (i & (HID * HID - 1));
        *(u16x4*)&d[di] = r;
    }
}

extern "C" void kernel_launch(void* const* d_in, const int* in_sizes, int n_in,
                              void* d_out, int out_size, void* d_ws, size_t ws_size,
                              hipStream_t stream) {
    const float* x    = (const float*)d_in[0];
    const float* w_ih = (const float*)d_in[1];
    const float* b_ih = (const float*)d_in[3];
    const float* b_hh = (const float*)d_in[4];
    const float* WH   = (const float*)d_in[5];
    const float* bH   = (const float*)d_in[6];
    const float* WT   = (const float*)d_in[7];
    const float* bT   = (const float*)d_in[8];
    const float* WC   = (const float*)d_in[9];
    const float* bC   = (const float*)d_in[10];

    float* out = (float*)d_out;               // [32768][1024] fp32, in-place h
    char*  ws  = (char*)d_ws;

    // ws layout (bytes): wih_bf 3.1MB | W_bf 31.5MB | ping 33.6MB | pong 33.6MB
    unsigned short* wih_bf = (unsigned short*)ws;
    unsigned short* W_bf   = (unsigned short*)(ws + (size_t)3 * HID * KGRU * 2);
    const size_t off_ping  = (size_t)3 * HID * KGRU * 2 + (size_t)15 * HID * HID * 2;
    unsigned short* ping   = (unsigned short*)(ws + off_ping);
    unsigned short* pong   = (unsigned short*)(ws + off_ping + (size_t)MH * HID * 2);
    // x_bf aliases pong (dead after GRU reads it; step0 then overwrites)

    const int LDS_BYTES = 147456;   // 144KB dynamic
    (void)hipFuncSetAttribute((const void*)gemm3<KGRU, true>,
                              hipFuncAttributeMaxDynamicSharedMemorySize, LDS_BYTES);
    (void)hipFuncSetAttribute((const void*)gemm3<HID, false>,
                              hipFuncAttributeMaxDynamicSharedMemorySize, LDS_BYTES);

    dim3 blk(256);
    dim3 gblk(512);
    dim3 ggrid(1024);    // (16384/256 m-tiles) x (1024/64 n-tiles)

    // weight conversions (every call; ws is re-poisoned)
    convP<<<1024, blk, 0, stream>>>(w_ih, wih_bf, 3 * HID * KGRU);
    convS<<<2048, blk, 0, stream>>>(WH, W_bf + 0 * HID * HID, 5 * HID * HID);
    convS<<<2048, blk, 0, stream>>>(WT, W_bf + 1 * HID * HID, 5 * HID * HID);
    convS<<<2048, blk, 0, stream>>>(WC, W_bf + 2 * HID * HID, 5 * HID * HID);

    for (int h = 0; h < 2; h++) {
        const float* xh   = x + (size_t)h * MH * KGRU;
        float*       outh = out + (size_t)h * MH * HID;

        convP<<<2048, blk, 0, stream>>>(xh, pong, MH * KGRU);

        // GRU: A = x_bf(pong), writes fp32 h -> outh, bf16 h -> ping
        gemm3<KGRU, true><<<ggrid, gblk, LDS_BYTES, stream>>>(
            pong, wih_bf, b_ih, b_ih + HID, b_ih + 2 * HID, b_hh, outh, ping);

        // 5 highway steps: bf16 A ping-pongs; fp32 h in-place in outh
        const unsigned short* src = ping;
        for (int s = 0; s < 5; s++) {
            unsigned short* dst = (s & 1) ? ping : pong;
            gemm3<HID, false><<<ggrid, gblk, LDS_BYTES, stream>>>(
                src, W_bf + (size_t)s * 3 * HID * HID,
                bH + s * HID, bT + s * HID, bC + s * HID, nullptr, outh, dst);
            src = dst;
        }
    }
}